// Round 4
// baseline (551.985 us; speedup 1.0000x reference)
//
#include <hip/hip_runtime.h>
#include <hip/hip_bf16.h>
#include <math.h>

typedef __bf16 bf16_t;
typedef __attribute__((ext_vector_type(8))) __bf16 bf16x8;
typedef __attribute__((ext_vector_type(4))) float f32x4;

// ---------------------------------------------------------------------------
// Dtype detector: view x as 16-bit words. If underlying data is fp32, the
// low-half words have uniform-random exponent fields -> some word has
// exponent >= 0xC0 with certainty over 4096 words. True bf16 N(0,1) data
// never does. Writes flag: 1 = inputs are fp32, 0 = bf16.
// ---------------------------------------------------------------------------
__global__ __launch_bounds__(256) void detect_dtype(
    const unsigned short* __restrict__ raw, int* __restrict__ flag)
{
    __shared__ int sflag;
    if (threadIdx.x == 0) sflag = 0;
    __syncthreads();
    int local = 0;
    for (int i = threadIdx.x; i < 4096; i += 256) {
        int e = (raw[i] >> 7) & 0xFF;
        if (e >= 0xC0) local = 1;
    }
    if (local) atomicOr(&sflag, 1);
    __syncthreads();
    if (threadIdx.x == 0) *flag = sflag;
}

// ---------------------------------------------------------------------------
// Convert n elements (n % 4 == 0) of src (fp32 if *flag else bf16) to bf16.
// ---------------------------------------------------------------------------
__global__ __launch_bounds__(256) void cvt_to_bf16(
    const void* __restrict__ src, bf16_t* __restrict__ dst, long n,
    const int* __restrict__ flag)
{
    const long i = ((long)blockIdx.x * 256 + threadIdx.x) * 4;
    if (i >= n) return;
    if (*flag) {
        const float4 v = *(const float4*)((const float*)src + i);
        dst[i + 0] = (bf16_t)v.x;
        dst[i + 1] = (bf16_t)v.y;
        dst[i + 2] = (bf16_t)v.z;
        dst[i + 3] = (bf16_t)v.w;
    } else {
        *(uint2*)(dst + i) = *(const uint2*)((const unsigned short*)src + i);
    }
}

// ---------------------------------------------------------------------------
// Generic C = A @ B^T (+bias / +mask epilogue) MFMA GEMM.
// A: [M,K] row-major, B: [N,K] row-major (bf16). C: [M,N] row-major,
// stored as bf16 (F32OUT=0) or fp32 (F32OUT=1).
// M,N multiples of 128; K multiple of 32.
// MODE 0: C = A@B^T + bias[n]            (bias fp32 or bf16 per *flag)
// MODE 1: C = mask[m,n] > 0.95 ? (A@B^T)*scale : -inf  (mask fp32/bf16)
// MODE 2: C = A@B^T
// ---------------------------------------------------------------------------
template <int MODE, int F32OUT>
__global__ __launch_bounds__(256) void gemm_bt(
    const bf16_t* __restrict__ A, const bf16_t* __restrict__ B,
    const void* __restrict__ bias, const void* __restrict__ mask,
    void* __restrict__ Cv,
    int M, int N, int K,
    long sA, long sB, long sC, long sM, float scale,
    const int* __restrict__ flag)
{
    const int b = blockIdx.z;
    A += (long)b * sA;
    B += (long)b * sB;

    int isf = 0;
    if (MODE == 0 || MODE == 1) isf = *flag;

    __shared__ bf16_t As[128 * 32];
    __shared__ bf16_t Bs[128 * 32];

    const int tid  = threadIdx.x;
    const int wave = tid >> 6;
    const int lane = tid & 63;
    const int quad = lane >> 4;
    const int r16  = lane & 15;
    const int wr   = wave >> 1;   // wave row (0..1) -> 64-row slab
    const int wc   = wave & 1;    // wave col (0..1) -> 64-col slab

    const int m0 = blockIdx.y * 128;
    const int n0 = blockIdx.x * 128;

    // staging: 128 rows x 32 cols = 4096 elems per buffer; 256 threads each
    // load TWO 16B chunks (8 bf16) per buffer: rows srow and srow+64.
    const int srow = tid >> 2;        // 0..63
    const int scol = (tid & 3) * 8;   // 0,8,16,24

    f32x4 acc[4][4] = {};

    for (int k0 = 0; k0 < K; k0 += 32) {
        const float4 a0 = *(const float4*)(A + (long)(m0 + srow)      * K + k0 + scol);
        const float4 a1 = *(const float4*)(A + (long)(m0 + srow + 64) * K + k0 + scol);
        const float4 b0 = *(const float4*)(B + (long)(n0 + srow)      * K + k0 + scol);
        const float4 b1 = *(const float4*)(B + (long)(n0 + srow + 64) * K + k0 + scol);
        *(float4*)(As + srow * 32 + scol)        = a0;
        *(float4*)(As + (srow + 64) * 32 + scol) = a1;
        *(float4*)(Bs + srow * 32 + scol)        = b0;
        *(float4*)(Bs + (srow + 64) * 32 + scol) = b1;
        __syncthreads();

        bf16x8 af[4], bfr[4];
#pragma unroll
        for (int i = 0; i < 4; i++)
            af[i] = *(const bf16x8*)(As + (wr * 64 + i * 16 + r16) * 32 + quad * 8);
#pragma unroll
        for (int j = 0; j < 4; j++)
            bfr[j] = *(const bf16x8*)(Bs + (wc * 64 + j * 16 + r16) * 32 + quad * 8);

#pragma unroll
        for (int i = 0; i < 4; i++)
#pragma unroll
            for (int j = 0; j < 4; j++)
                acc[i][j] = __builtin_amdgcn_mfma_f32_16x16x32_bf16(af[i], bfr[j], acc[i][j], 0, 0, 0);
        __syncthreads();
    }

    // Epilogue. C/D layout (16x16x32): col = lane&15, row = quad*4 + reg.
#pragma unroll
    for (int i = 0; i < 4; i++) {
#pragma unroll
        for (int j = 0; j < 4; j++) {
            const int gn = n0 + wc * 64 + j * 16 + r16;
            float bval = 0.f;
            if (MODE == 0)
                bval = isf ? ((const float*)bias)[gn]
                           : (float)((const bf16_t*)bias)[gn];
#pragma unroll
            for (int reg = 0; reg < 4; reg++) {
                const int gm = m0 + wr * 64 + i * 16 + quad * 4 + reg;
                float v = acc[i][j][reg];
                if (MODE == 0) v += bval;
                if (MODE == 1) {
                    v *= scale;
                    const long midx = (long)b * sM + (long)gm * N + gn;
                    const float mv = isf ? ((const float*)mask)[midx]
                                         : (float)((const bf16_t*)mask)[midx];
                    v = (mv > 0.95f) ? v : -INFINITY;
                }
                const long cidx = (long)b * sC + (long)gm * N + gn;
                if (F32OUT) ((float*)Cv)[cidx] = v;
                else        ((bf16_t*)Cv)[cidx] = (bf16_t)v;
            }
        }
    }
}

// ---------------------------------------------------------------------------
// V [B][rows][cols] -> VT [B][cols][rows]  (rows=S=4096, cols=D=512)
// ---------------------------------------------------------------------------
__global__ __launch_bounds__(256) void transpose_k(
    const bf16_t* __restrict__ in, bf16_t* __restrict__ out, int rows, int cols)
{
    __shared__ bf16_t tile[32][33];
    const int b = blockIdx.z;
    in  += (long)b * rows * cols;
    out += (long)b * rows * cols;
    const int r0 = blockIdx.y * 32;
    const int c0 = blockIdx.x * 32;
    const int tx = threadIdx.x;   // 0..31
    const int ty = threadIdx.y;   // 0..7
#pragma unroll
    for (int i = 0; i < 4; i++)
        tile[ty + 8 * i][tx] = in[(long)(r0 + ty + 8 * i) * cols + c0 + tx];
    __syncthreads();
#pragma unroll
    for (int i = 0; i < 4; i++)
        out[(long)(c0 + ty + 8 * i) * rows + r0 + tx] = tile[tx][ty + 8 * i];
}

// ---------------------------------------------------------------------------
// In-place row softmax over [nrows x 4096] bf16 (rows contain -inf masks).
// One 256-thread block per row, 16 elements/thread.
// ---------------------------------------------------------------------------
__global__ __launch_bounds__(256) void softmax_rows(bf16_t* __restrict__ P)
{
    const long row = blockIdx.x;
    bf16_t* p = P + row * 4096;
    const int tid  = threadIdx.x;
    const int wave = tid >> 6;
    const int lane = tid & 63;

    float v[16];
    float m = -INFINITY;
#pragma unroll
    for (int i = 0; i < 16; i++) {
        v[i] = (float)p[tid + (i << 8)];
        m = fmaxf(m, v[i]);
    }
#pragma unroll
    for (int off = 32; off; off >>= 1) m = fmaxf(m, __shfl_xor(m, off, 64));
    __shared__ float redm[4];
    if (lane == 0) redm[wave] = m;
    __syncthreads();
    m = fmaxf(fmaxf(redm[0], redm[1]), fmaxf(redm[2], redm[3]));

    float s = 0.f;
#pragma unroll
    for (int i = 0; i < 16; i++) {
        v[i] = __expf(v[i] - m);
        s += v[i];
    }
#pragma unroll
    for (int off = 32; off; off >>= 1) s += __shfl_xor(s, off, 64);
    __shared__ float reds[4];
    if (lane == 0) reds[wave] = s;
    __syncthreads();
    s = reds[0] + reds[1] + reds[2] + reds[3];

    const float inv = 1.f / s;
#pragma unroll
    for (int i = 0; i < 16; i++) p[tid + (i << 8)] = (bf16_t)(v[i] * inv);
}

// ---------------------------------------------------------------------------
extern "C" void kernel_launch(void* const* d_in, const int* in_sizes, int n_in,
                              void* d_out, int out_size, void* d_ws, size_t ws_size,
                              hipStream_t stream)
{
    constexpr int B = 2, S = 4096, D = 512;
    constexpr int BS = B * S;                  // 8192
    constexpr long QKV_ELEMS = (long)BS * D;   // 4 Mi elems
    constexpr long W_ELEMS   = (long)D * D;    // 256 Ki elems

    const void* x_raw = d_in[0];
    const void* mask  = d_in[1];
    const void* Wq    = d_in[2];
    const void* bq    = d_in[3];
    const void* Wk    = d_in[4];
    const void* bk    = d_in[5];
    const void* Wv    = d_in[6];
    const void* bv    = d_in[7];
    const void* Wo    = d_in[8];
    const void* bo    = d_in[9];

    bf16_t* Q   = (bf16_t*)d_ws;
    bf16_t* Kp  = Q + QKV_ELEMS;
    bf16_t* V   = Kp + QKV_ELEMS;
    bf16_t* VT  = V + QKV_ELEMS;
    bf16_t* T   = V;                           // alias: V dead after transpose
    bf16_t* SC  = VT + QKV_ELEMS;              // [B*S, S] scores -> P in place
    bf16_t* Xc  = SC + (long)BS * S;           // bf16 copy of x
    bf16_t* Wqc = Xc + QKV_ELEMS;
    bf16_t* Wkc = Wqc + W_ELEMS;
    bf16_t* Wvc = Wkc + W_ELEMS;
    bf16_t* Woc = Wvc + W_ELEMS;
    int*    flag = (int*)(Woc + W_ELEMS);

    const float scale = 0.044194173824159216f; // 1/sqrt(512)
    dim3 blk(256);

    // 1) detect input dtype (fp32 vs bf16) on-device
    detect_dtype<<<1, blk, 0, stream>>>((const unsigned short*)x_raw, flag);

    // 2) produce bf16 copies of x and the weight matrices
    cvt_to_bf16<<<dim3((int)(QKV_ELEMS / 1024)), blk, 0, stream>>>(x_raw, Xc, QKV_ELEMS, flag);
    cvt_to_bf16<<<dim3((int)(W_ELEMS / 1024)), blk, 0, stream>>>(Wq, Wqc, W_ELEMS, flag);
    cvt_to_bf16<<<dim3((int)(W_ELEMS / 1024)), blk, 0, stream>>>(Wk, Wkc, W_ELEMS, flag);
    cvt_to_bf16<<<dim3((int)(W_ELEMS / 1024)), blk, 0, stream>>>(Wv, Wvc, W_ELEMS, flag);
    cvt_to_bf16<<<dim3((int)(W_ELEMS / 1024)), blk, 0, stream>>>(Wo, Woc, W_ELEMS, flag);

    // 3) QKV projections: [8192,512] @ [512,512]^T + bias  (bf16 out)
    gemm_bt<0, 0><<<dim3(4, 64, 1), blk, 0, stream>>>(Xc, Wqc, bq, nullptr, Q,
        BS, D, D, 0, 0, 0, 0, 0.f, flag);
    gemm_bt<0, 0><<<dim3(4, 64, 1), blk, 0, stream>>>(Xc, Wkc, bk, nullptr, Kp,
        BS, D, D, 0, 0, 0, 0, 0.f, flag);
    gemm_bt<0, 0><<<dim3(4, 64, 1), blk, 0, stream>>>(Xc, Wvc, bv, nullptr, V,
        BS, D, D, 0, 0, 0, 0, 0.f, flag);

    // 4) V^T per batch: [S,D] -> [D,S]
    transpose_k<<<dim3(D / 32, S / 32, B), dim3(32, 8), 0, stream>>>(V, VT, S, D);

    // 5) scores = mask ? (Q @ K^T) * scale : -inf   (per batch, bf16 out)
    gemm_bt<1, 0><<<dim3(S / 128, S / 128, B), blk, 0, stream>>>(Q, Kp, nullptr, mask, SC,
        S, S, D, (long)S * D, (long)S * D, (long)S * S, (long)S * S, scale, flag);

    // 6) softmax rows in place
    softmax_rows<<<dim3(BS), blk, 0, stream>>>(SC);

    // 7) T[b][d][q] = sum_k VT[b][d][k] * P[b][q][k]   (M=D, N=S, K=S, bf16 out)
    gemm_bt<2, 0><<<dim3(S / 128, D / 128, B), blk, 0, stream>>>(VT, SC, nullptr, nullptr, T,
        D, S, S, (long)D * S, (long)S * S, (long)D * S, 0, 0.f, flag);

    // 8) out = Z @ Wo^T + bo, Z = flat(T) viewed [B*S, D] — FP32 output
    gemm_bt<0, 1><<<dim3(4, 64, 1), blk, 0, stream>>>(T, Woc, bo, nullptr, d_out,
        BS, D, D, 0, 0, 0, 0, 0.f, flag);
}

// Round 5
// 411.311 us; speedup vs baseline: 1.3420x; 1.3420x over previous
//
#include <hip/hip_runtime.h>
#include <hip/hip_bf16.h>
#include <math.h>

typedef __bf16 bf16_t;
typedef __attribute__((ext_vector_type(8))) __bf16 bf16x8;
typedef __attribute__((ext_vector_type(4))) float f32x4;

// Async global->LDS 16B copy. LDS dest must be wave-uniform base + lane*16,
// which our staging layout satisfies (lds byte addr == tid*16 (+const)).
__device__ __forceinline__ void load16_lds(const bf16_t* g, bf16_t* l) {
    __builtin_amdgcn_global_load_lds(
        (const __attribute__((address_space(1))) void*)g,
        (__attribute__((address_space(3))) void*)l, 16, 0, 0);
}

// ---------------------------------------------------------------------------
// fp32 -> bf16 conversion (n % 4 == 0)
// ---------------------------------------------------------------------------
__global__ __launch_bounds__(256) void cvt_to_bf16(
    const float* __restrict__ src, bf16_t* __restrict__ dst, long n)
{
    const long i = ((long)blockIdx.x * 256 + threadIdx.x) * 4;
    if (i >= n) return;
    const float4 v = *(const float4*)(src + i);
    dst[i + 0] = (bf16_t)v.x;
    dst[i + 1] = (bf16_t)v.y;
    dst[i + 2] = (bf16_t)v.z;
    dst[i + 3] = (bf16_t)v.w;
}

// ---------------------------------------------------------------------------
// Generic C = A @ B^T MFMA GEMM, 128x128 tile, BK=32, global_load_lds staging.
// A: [M,K] row-major, B: [N,K] row-major (bf16). C row-major.
// MODE 0: C = A@B^T + bias[n] (bias fp32)
// MODE 1: C = (A@B^T) * scale
// MODE 2: C = A@B^T
// F32OUT: store fp32 instead of bf16.
// ---------------------------------------------------------------------------
template <int MODE, int F32OUT>
__global__ __launch_bounds__(256) void gemm_bt(
    const bf16_t* __restrict__ A, const bf16_t* __restrict__ B,
    const float* __restrict__ bias, void* __restrict__ Cv,
    int M, int N, int K,
    long sA, long sB, long sC, float scale)
{
    const int b = blockIdx.z;
    A += (long)b * sA;
    B += (long)b * sB;

    __shared__ bf16_t As[128 * 32];
    __shared__ bf16_t Bs[128 * 32];

    const int tid  = threadIdx.x;
    const int wave = tid >> 6;
    const int lane = tid & 63;
    const int quad = lane >> 4;
    const int r16  = lane & 15;
    const int wr   = wave >> 1;
    const int wc   = wave & 1;

    const int m0 = blockIdx.y * 128;
    const int n0 = blockIdx.x * 128;

    // staging: lds byte addr = tid*16 (+2048 elems for second half)
    const int srow = tid >> 2;        // 0..63
    const int scol = (tid & 3) * 8;   // 0,8,16,24

    const bf16_t* gA0 = A + (long)(m0 + srow) * K + scol;
    const bf16_t* gA1 = gA0 + (long)64 * K;
    const bf16_t* gB0 = B + (long)(n0 + srow) * K + scol;
    const bf16_t* gB1 = gB0 + (long)64 * K;
    bf16_t* lA = As + tid * 8;
    bf16_t* lB = Bs + tid * 8;

    f32x4 acc[4][4] = {};

    for (int k0 = 0; k0 < K; k0 += 32) {
        load16_lds(gA0 + k0, lA);
        load16_lds(gA1 + k0, lA + 2048);
        load16_lds(gB0 + k0, lB);
        load16_lds(gB1 + k0, lB + 2048);
        __syncthreads();

        bf16x8 af[4], bfr[4];
#pragma unroll
        for (int i = 0; i < 4; i++)
            af[i] = *(const bf16x8*)(As + (wr * 64 + i * 16 + r16) * 32 + quad * 8);
#pragma unroll
        for (int j = 0; j < 4; j++)
            bfr[j] = *(const bf16x8*)(Bs + (wc * 64 + j * 16 + r16) * 32 + quad * 8);

#pragma unroll
        for (int i = 0; i < 4; i++)
#pragma unroll
            for (int j = 0; j < 4; j++)
                acc[i][j] = __builtin_amdgcn_mfma_f32_16x16x32_bf16(af[i], bfr[j], acc[i][j], 0, 0, 0);
        __syncthreads();
    }

    // Epilogue. C/D layout (16x16x32): col = lane&15, row = quad*4 + reg.
#pragma unroll
    for (int i = 0; i < 4; i++) {
#pragma unroll
        for (int j = 0; j < 4; j++) {
            const int gn = n0 + wc * 64 + j * 16 + r16;
            float bval = 0.f;
            if (MODE == 0) bval = bias[gn];
#pragma unroll
            for (int reg = 0; reg < 4; reg++) {
                const int gm = m0 + wr * 64 + i * 16 + quad * 4 + reg;
                float v = acc[i][j][reg];
                if (MODE == 0) v += bval;
                if (MODE == 1) v *= scale;
                const long cidx = (long)b * sC + (long)gm * N + gn;
                if (F32OUT) ((float*)Cv)[cidx] = v;
                else        ((bf16_t*)Cv)[cidx] = (bf16_t)v;
            }
        }
    }
}

// ---------------------------------------------------------------------------
// Fused QKV projection: X[8192,512] @ {Wq,Wk,Wv}^T + {bq,bk,bv}.
// Grid (12, 64): blockIdx.x>>2 selects matrix, (blockIdx.x&3)*128 = n0.
// ---------------------------------------------------------------------------
__global__ __launch_bounds__(256) void qkv_gemm(
    const bf16_t* __restrict__ X,
    const bf16_t* __restrict__ Wq, const bf16_t* __restrict__ Wk, const bf16_t* __restrict__ Wv,
    const float* __restrict__ bq, const float* __restrict__ bk, const float* __restrict__ bv,
    bf16_t* __restrict__ Q, bf16_t* __restrict__ Kout, bf16_t* __restrict__ V)
{
    constexpr int K = 512, N = 512;
    const int sel = blockIdx.x >> 2;
    const bf16_t* B = (sel == 0) ? Wq : (sel == 1) ? Wk : Wv;
    const float* bias = (sel == 0) ? bq : (sel == 1) ? bk : bv;
    bf16_t* C = (sel == 0) ? Q : (sel == 1) ? Kout : V;

    __shared__ bf16_t As[128 * 32];
    __shared__ bf16_t Bs[128 * 32];

    const int tid  = threadIdx.x;
    const int wave = tid >> 6;
    const int lane = tid & 63;
    const int quad = lane >> 4;
    const int r16  = lane & 15;
    const int wr   = wave >> 1;
    const int wc   = wave & 1;

    const int m0 = blockIdx.y * 128;
    const int n0 = (blockIdx.x & 3) * 128;

    const int srow = tid >> 2;
    const int scol = (tid & 3) * 8;

    const bf16_t* gA0 = X + (long)(m0 + srow) * K + scol;
    const bf16_t* gA1 = gA0 + (long)64 * K;
    const bf16_t* gB0 = B + (long)(n0 + srow) * K + scol;
    const bf16_t* gB1 = gB0 + (long)64 * K;
    bf16_t* lA = As + tid * 8;
    bf16_t* lB = Bs + tid * 8;

    f32x4 acc[4][4] = {};

    for (int k0 = 0; k0 < K; k0 += 32) {
        load16_lds(gA0 + k0, lA);
        load16_lds(gA1 + k0, lA + 2048);
        load16_lds(gB0 + k0, lB);
        load16_lds(gB1 + k0, lB + 2048);
        __syncthreads();

        bf16x8 af[4], bfr[4];
#pragma unroll
        for (int i = 0; i < 4; i++)
            af[i] = *(const bf16x8*)(As + (wr * 64 + i * 16 + r16) * 32 + quad * 8);
#pragma unroll
        for (int j = 0; j < 4; j++)
            bfr[j] = *(const bf16x8*)(Bs + (wc * 64 + j * 16 + r16) * 32 + quad * 8);

#pragma unroll
        for (int i = 0; i < 4; i++)
#pragma unroll
            for (int j = 0; j < 4; j++)
                acc[i][j] = __builtin_amdgcn_mfma_f32_16x16x32_bf16(af[i], bfr[j], acc[i][j], 0, 0, 0);
        __syncthreads();
    }

#pragma unroll
    for (int i = 0; i < 4; i++) {
#pragma unroll
        for (int j = 0; j < 4; j++) {
            const int gn = n0 + wc * 64 + j * 16 + r16;
            const float bval = bias[gn];
#pragma unroll
            for (int reg = 0; reg < 4; reg++) {
                const int gm = m0 + wr * 64 + i * 16 + quad * 4 + reg;
                C[(long)gm * N + gn] = (bf16_t)(acc[i][j][reg] + bval);
            }
        }
    }
}

// ---------------------------------------------------------------------------
// V [B][rows][cols] -> VT [B][cols][rows]  (rows=S=4096, cols=D=512)
// ---------------------------------------------------------------------------
__global__ __launch_bounds__(256) void transpose_k(
    const bf16_t* __restrict__ in, bf16_t* __restrict__ out, int rows, int cols)
{
    __shared__ bf16_t tile[32][33];
    const int b = blockIdx.z;
    in  += (long)b * rows * cols;
    out += (long)b * rows * cols;
    const int r0 = blockIdx.y * 32;
    const int c0 = blockIdx.x * 32;
    const int tx = threadIdx.x;
    const int ty = threadIdx.y;
#pragma unroll
    for (int i = 0; i < 4; i++)
        tile[ty + 8 * i][tx] = in[(long)(r0 + ty + 8 * i) * cols + c0 + tx];
    __syncthreads();
#pragma unroll
    for (int i = 0; i < 4; i++)
        out[(long)(c0 + ty + 8 * i) * rows + r0 + tx] = tile[tx][ty + 8 * i];
}

// ---------------------------------------------------------------------------
// Fused mask + row softmax over [8192 x 4096]: in-place on scaled scores.
// keep = mask[row][k] > 0.95 (fp32, bit-exact vs ref); else -inf.
// One block/row, 16 contiguous elems/thread (32B/lane -> coalesced).
// ---------------------------------------------------------------------------
__global__ __launch_bounds__(256) void softmax_mask(
    bf16_t* __restrict__ P, const float* __restrict__ mask)
{
    const long row = blockIdx.x;
    bf16_t* p = P + row * 4096;
    const float* mrow = mask + row * 4096;
    const int tid  = threadIdx.x;
    const int wave = tid >> 6;
    const int lane = tid & 63;
    const int base = tid * 16;

    bf16x8 s0 = *(const bf16x8*)(p + base);
    bf16x8 s1 = *(const bf16x8*)(p + base + 8);
    float mk[16];
#pragma unroll
    for (int c = 0; c < 4; c++) {
        const float4 mv = *(const float4*)(mrow + base + c * 4);
        mk[c * 4 + 0] = mv.x; mk[c * 4 + 1] = mv.y;
        mk[c * 4 + 2] = mv.z; mk[c * 4 + 3] = mv.w;
    }

    float v[16];
    float m = -INFINITY;
#pragma unroll
    for (int i = 0; i < 8; i++) {
        v[i]     = (mk[i]     > 0.95f) ? (float)s0[i] : -INFINITY;
        v[i + 8] = (mk[i + 8] > 0.95f) ? (float)s1[i] : -INFINITY;
    }
#pragma unroll
    for (int i = 0; i < 16; i++) m = fmaxf(m, v[i]);
#pragma unroll
    for (int off = 32; off; off >>= 1) m = fmaxf(m, __shfl_xor(m, off, 64));
    __shared__ float redm[4];
    if (lane == 0) redm[wave] = m;
    __syncthreads();
    m = fmaxf(fmaxf(redm[0], redm[1]), fmaxf(redm[2], redm[3]));

    float s = 0.f;
#pragma unroll
    for (int i = 0; i < 16; i++) {
        v[i] = __expf(v[i] - m);
        s += v[i];
    }
#pragma unroll
    for (int off = 32; off; off >>= 1) s += __shfl_xor(s, off, 64);
    __shared__ float reds[4];
    if (lane == 0) reds[wave] = s;
    __syncthreads();
    s = reds[0] + reds[1] + reds[2] + reds[3];

    const float inv = 1.f / s;
    bf16x8 o0, o1;
#pragma unroll
    for (int i = 0; i < 8; i++) {
        o0[i] = (bf16_t)(v[i] * inv);
        o1[i] = (bf16_t)(v[i + 8] * inv);
    }
    *(bf16x8*)(p + base)     = o0;
    *(bf16x8*)(p + base + 8) = o1;
}

// ---------------------------------------------------------------------------
extern "C" void kernel_launch(void* const* d_in, const int* in_sizes, int n_in,
                              void* d_out, int out_size, void* d_ws, size_t ws_size,
                              hipStream_t stream)
{
    constexpr int B = 2, S = 4096, D = 512;
    constexpr int BS = B * S;                  // 8192
    constexpr long QKV_ELEMS = (long)BS * D;   // 4 Mi
    constexpr long W_ELEMS   = (long)D * D;    // 256 Ki

    const float* x_raw = (const float*)d_in[0];
    const float* mask  = (const float*)d_in[1];
    const float* Wq    = (const float*)d_in[2];
    const float* bq    = (const float*)d_in[3];
    const float* Wk    = (const float*)d_in[4];
    const float* bk    = (const float*)d_in[5];
    const float* Wv    = (const float*)d_in[6];
    const float* bv    = (const float*)d_in[7];
    const float* Wo    = (const float*)d_in[8];
    const float* bo    = (const float*)d_in[9];

    bf16_t* Q   = (bf16_t*)d_ws;
    bf16_t* Kp  = Q + QKV_ELEMS;
    bf16_t* V   = Kp + QKV_ELEMS;
    bf16_t* VT  = V + QKV_ELEMS;
    bf16_t* T   = V;                           // alias: V dead after transpose
    bf16_t* SC  = VT + QKV_ELEMS;              // [B*S, S] scores -> P in place
    bf16_t* Xc  = SC + (long)BS * S;
    bf16_t* Wqc = Xc + QKV_ELEMS;
    bf16_t* Wkc = Wqc + W_ELEMS;
    bf16_t* Wvc = Wkc + W_ELEMS;
    bf16_t* Woc = Wvc + W_ELEMS;

    const float scale = 0.044194173824159216f; // 1/sqrt(512)
    dim3 blk(256);

    // 1) convert fp32 inputs to bf16
    cvt_to_bf16<<<dim3((int)(QKV_ELEMS / 1024)), blk, 0, stream>>>(x_raw, Xc, QKV_ELEMS);
    cvt_to_bf16<<<dim3((int)(W_ELEMS / 1024)), blk, 0, stream>>>(Wq, Wqc, W_ELEMS);
    cvt_to_bf16<<<dim3((int)(W_ELEMS / 1024)), blk, 0, stream>>>(Wk, Wkc, W_ELEMS);
    cvt_to_bf16<<<dim3((int)(W_ELEMS / 1024)), blk, 0, stream>>>(Wv, Wvc, W_ELEMS);
    cvt_to_bf16<<<dim3((int)(W_ELEMS / 1024)), blk, 0, stream>>>(Wo, Woc, W_ELEMS);

    // 2) fused QKV projections (768 blocks -> ~3 blocks/CU)
    qkv_gemm<<<dim3(12, 64), blk, 0, stream>>>(Xc, Wqc, Wkc, Wvc, bq, bk, bv, Q, Kp, V);

    // 3) V^T per batch
    transpose_k<<<dim3(D / 32, S / 32, B), dim3(32, 8), 0, stream>>>(V, VT, S, D);

    // 4) raw scaled scores = (Q @ K^T) * scale  (mask deferred to softmax)
    gemm_bt<1, 0><<<dim3(S / 128, S / 128, B), blk, 0, stream>>>(Q, Kp, nullptr, SC,
        S, S, D, (long)S * D, (long)S * D, (long)S * S, scale);

    // 5) fused mask + softmax (streaming, BW-bound)
    softmax_mask<<<dim3(BS), blk, 0, stream>>>(SC, mask);

    // 6) T[b][d][q] = sum_k VT[b][d][k] * P[b][q][k]
    gemm_bt<2, 0><<<dim3(S / 128, D / 128, B), blk, 0, stream>>>(VT, SC, nullptr, T,
        D, S, S, (long)D * S, (long)S * S, (long)D * S, 1.f);

    // 7) out = flat(T)[BS,D] @ Wo^T + bo  -> fp32 d_out
    gemm_bt<0, 1><<<dim3(4, 64, 1), blk, 0, stream>>>(T, Woc, bo, d_out,
        BS, D, D, 0, 0, 0, 0.f);
}

// Round 6
// 395.028 us; speedup vs baseline: 1.3973x; 1.0412x over previous
//
#include <hip/hip_runtime.h>
#include <hip/hip_bf16.h>
#include <math.h>

typedef __bf16 bf16_t;
typedef __attribute__((ext_vector_type(8))) __bf16 bf16x8;
typedef __attribute__((ext_vector_type(4))) float f32x4;

constexpr int B_ = 2, S_ = 4096, D_ = 512;
constexpr int BS_ = B_ * S_;

// Async global->LDS 16B copy. LDS dest must be wave-uniform base + lane*16.
__device__ __forceinline__ void load16_lds(const bf16_t* g, bf16_t* l) {
    __builtin_amdgcn_global_load_lds(
        (const __attribute__((address_space(1))) void*)g,
        (__attribute__((address_space(3))) void*)l, 16, 0, 0);
}

// ---------------------------------------------------------------------------
// fp32 -> bf16 conversion (n % 4 == 0)
// ---------------------------------------------------------------------------
__global__ __launch_bounds__(256) void cvt_to_bf16(
    const float* __restrict__ src, bf16_t* __restrict__ dst, long n)
{
    const long i = ((long)blockIdx.x * 256 + threadIdx.x) * 4;
    if (i >= n) return;
    const float4 v = *(const float4*)(src + i);
    dst[i + 0] = (bf16_t)v.x;
    dst[i + 1] = (bf16_t)v.y;
    dst[i + 2] = (bf16_t)v.z;
    dst[i + 3] = (bf16_t)v.w;
}

// ---------------------------------------------------------------------------
// Fused QKV projection: X[8192,512] @ {Wq,Wk,Wv}^T + {bq,bk,bv}.
// ---------------------------------------------------------------------------
__global__ __launch_bounds__(256) void qkv_gemm(
    const bf16_t* __restrict__ X,
    const bf16_t* __restrict__ Wq, const bf16_t* __restrict__ Wk, const bf16_t* __restrict__ Wv,
    const float* __restrict__ bq, const float* __restrict__ bk, const float* __restrict__ bv,
    bf16_t* __restrict__ Q, bf16_t* __restrict__ Kout, bf16_t* __restrict__ V)
{
    constexpr int K = 512, N = 512;
    const int sel = blockIdx.x >> 2;
    const bf16_t* B = (sel == 0) ? Wq : (sel == 1) ? Wk : Wv;
    const float* bias = (sel == 0) ? bq : (sel == 1) ? bk : bv;
    bf16_t* C = (sel == 0) ? Q : (sel == 1) ? Kout : V;

    __shared__ bf16_t As[128 * 32];
    __shared__ bf16_t Bs[128 * 32];

    const int tid  = threadIdx.x;
    const int wave = tid >> 6;
    const int lane = tid & 63;
    const int quad = lane >> 4;
    const int r16  = lane & 15;
    const int wr   = wave >> 1;
    const int wc   = wave & 1;

    const int m0 = blockIdx.y * 128;
    const int n0 = (blockIdx.x & 3) * 128;

    const int srow = tid >> 2;
    const int scol = (tid & 3) * 8;

    const bf16_t* gA0 = X + (long)(m0 + srow) * K + scol;
    const bf16_t* gA1 = gA0 + (long)64 * K;
    const bf16_t* gB0 = B + (long)(n0 + srow) * K + scol;
    const bf16_t* gB1 = gB0 + (long)64 * K;
    bf16_t* lA = As + tid * 8;
    bf16_t* lB = Bs + tid * 8;

    f32x4 acc[4][4] = {};

    for (int k0 = 0; k0 < K; k0 += 32) {
        load16_lds(gA0 + k0, lA);
        load16_lds(gA1 + k0, lA + 2048);
        load16_lds(gB0 + k0, lB);
        load16_lds(gB1 + k0, lB + 2048);
        __syncthreads();

        bf16x8 af[4], bfr[4];
#pragma unroll
        for (int i = 0; i < 4; i++)
            af[i] = *(const bf16x8*)(As + (wr * 64 + i * 16 + r16) * 32 + quad * 8);
#pragma unroll
        for (int j = 0; j < 4; j++)
            bfr[j] = *(const bf16x8*)(Bs + (wc * 64 + j * 16 + r16) * 32 + quad * 8);

#pragma unroll
        for (int i = 0; i < 4; i++)
#pragma unroll
            for (int j = 0; j < 4; j++)
                acc[i][j] = __builtin_amdgcn_mfma_f32_16x16x32_bf16(af[i], bfr[j], acc[i][j], 0, 0, 0);
        __syncthreads();
    }

#pragma unroll
    for (int i = 0; i < 4; i++) {
#pragma unroll
        for (int j = 0; j < 4; j++) {
            const int gn = n0 + wc * 64 + j * 16 + r16;
            const float bval = bias[gn];
#pragma unroll
            for (int reg = 0; reg < 4; reg++) {
                const int gm = m0 + wr * 64 + i * 16 + quad * 4 + reg;
                C[(long)gm * N + gn] = (bf16_t)(acc[i][j][reg] + bval);
            }
        }
    }
}

// ---------------------------------------------------------------------------
// Scores GEMM with fused mask + exp + row-sum accumulation.
// E[b,q,k] = mask[b,q,k] > 0.95 ? exp(scale * (Q.K)) : 0   (bf16, unnormalized)
// rowsum[b*S + q] += per-row sums (fp32 atomics; must be zeroed beforehand).
// Epilogue goes through a per-wave LDS slice so mask loads are float4 and
// stores are bf16x8 (coalesced).
// ---------------------------------------------------------------------------
__global__ __launch_bounds__(256) void scores_gemm(
    const bf16_t* __restrict__ Q, const bf16_t* __restrict__ Km,
    const float* __restrict__ mask, bf16_t* __restrict__ SC,
    float* __restrict__ rowsum, float scale)
{
    constexpr int S = S_, K = D_;
    const int b = blockIdx.z;
    const bf16_t* A = Q + (long)b * S * K;
    const bf16_t* Bm = Km + (long)b * S * K;

    __shared__ char smem[16384];
    bf16_t* As = (bf16_t*)smem;
    bf16_t* Bs = (bf16_t*)(smem + 8192);

    const int tid  = threadIdx.x;
    const int wave = tid >> 6;
    const int lane = tid & 63;
    const int quad = lane >> 4;
    const int r16  = lane & 15;
    const int wr   = wave >> 1;
    const int wc   = wave & 1;

    const int m0 = blockIdx.y * 128;
    const int n0 = blockIdx.x * 128;

    const int srow = tid >> 2;
    const int scol = (tid & 3) * 8;

    const bf16_t* gA0 = A + (long)(m0 + srow) * K + scol;
    const bf16_t* gA1 = gA0 + (long)64 * K;
    const bf16_t* gB0 = Bm + (long)(n0 + srow) * K + scol;
    const bf16_t* gB1 = gB0 + (long)64 * K;
    bf16_t* lA = As + tid * 8;
    bf16_t* lB = Bs + tid * 8;

    f32x4 acc[4][4] = {};

    for (int k0 = 0; k0 < K; k0 += 32) {
        load16_lds(gA0 + k0, lA);
        load16_lds(gA1 + k0, lA + 2048);
        load16_lds(gB0 + k0, lB);
        load16_lds(gB1 + k0, lB + 2048);
        __syncthreads();

        bf16x8 af[4], bfr[4];
#pragma unroll
        for (int i = 0; i < 4; i++)
            af[i] = *(const bf16x8*)(As + (wr * 64 + i * 16 + r16) * 32 + quad * 8);
#pragma unroll
        for (int j = 0; j < 4; j++)
            bfr[j] = *(const bf16x8*)(Bs + (wc * 64 + j * 16 + r16) * 32 + quad * 8);

#pragma unroll
        for (int i = 0; i < 4; i++)
#pragma unroll
            for (int j = 0; j < 4; j++)
                acc[i][j] = __builtin_amdgcn_mfma_f32_16x16x32_bf16(af[i], bfr[j], acc[i][j], 0, 0, 0);
        __syncthreads();
    }

    // Epilogue: per-wave LDS swizzle (4 KB slice each), coalesced mask/stores.
    float* wlds = (float*)smem + wave * 1024;   // 16 rows x 64 cols fp32
    const int erow = lane >> 2;                 // 0..15
    const int ecg  = lane & 3;                  // col group: cols ecg*16..+15
    const long mbase = (long)b * S * S;

#pragma unroll
    for (int i = 0; i < 4; i++) {
#pragma unroll
        for (int j = 0; j < 4; j++)
#pragma unroll
            for (int reg = 0; reg < 4; reg++)
                wlds[(quad * 4 + reg) * 64 + j * 16 + r16] = acc[i][j][reg];
        __syncthreads();   // order LDS write -> read (uniform barrier)

        float v[16];
#pragma unroll
        for (int c = 0; c < 4; c++) {
            const float4 t = *(const float4*)(wlds + erow * 64 + ecg * 16 + c * 4);
            v[c * 4 + 0] = t.x; v[c * 4 + 1] = t.y;
            v[c * 4 + 2] = t.z; v[c * 4 + 3] = t.w;
        }

        const int gm = m0 + wr * 64 + i * 16 + erow;
        const int gn = n0 + wc * 64 + ecg * 16;
        const float* mp = mask + mbase + (long)gm * S + gn;

        float e[16];
        float rsum = 0.f;
#pragma unroll
        for (int c = 0; c < 4; c++) {
            const float4 mk = *(const float4*)(mp + c * 4);
            e[c * 4 + 0] = (mk.x > 0.95f) ? __expf(v[c * 4 + 0] * scale) : 0.f;
            e[c * 4 + 1] = (mk.y > 0.95f) ? __expf(v[c * 4 + 1] * scale) : 0.f;
            e[c * 4 + 2] = (mk.z > 0.95f) ? __expf(v[c * 4 + 2] * scale) : 0.f;
            e[c * 4 + 3] = (mk.w > 0.95f) ? __expf(v[c * 4 + 3] * scale) : 0.f;
        }
        bf16x8 o0, o1;
#pragma unroll
        for (int t = 0; t < 8; t++) {
            rsum += e[t] + e[t + 8];
            o0[t] = (bf16_t)e[t];
            o1[t] = (bf16_t)e[t + 8];
        }
        bf16_t* cp = SC + mbase + (long)gm * S + gn;
        *(bf16x8*)cp       = o0;
        *(bf16x8*)(cp + 8) = o1;

        rsum += __shfl_xor(rsum, 1, 64);
        rsum += __shfl_xor(rsum, 2, 64);
        if (ecg == 0) atomicAdd(&rowsum[b * S + gm], rsum);
        __syncthreads();   // protect wlds before next i overwrites
    }
}

// ---------------------------------------------------------------------------
// PV split-K: part[(ks*B + b)] += VT-tile @ E-tile over K chunk.
// PMODE 0: fp32 partial store; 1: bf16 partial store;
// PMODE 2: direct bf16 output normalized by rowsum (KS==1).
// A = VT [D,S] per batch; B = SC/E [S rows (q), S cols (k)]; out [D,S].
// ---------------------------------------------------------------------------
template <int PMODE, int KS>
__global__ __launch_bounds__(256) void pv_gemm(
    const bf16_t* __restrict__ VT, const bf16_t* __restrict__ SC,
    const float* __restrict__ rowsum, void* __restrict__ outp)
{
    constexpr int S = S_, D = D_;
    constexpr int KC = S / KS;
    const int z  = blockIdx.z;
    const int b  = z / KS;
    const int ks = z % KS;

    const bf16_t* A  = VT + (long)b * D * S;
    const bf16_t* Bm = SC + (long)b * S * S;

    __shared__ bf16_t As[128 * 32];
    __shared__ bf16_t Bs[128 * 32];

    const int tid  = threadIdx.x;
    const int wave = tid >> 6;
    const int lane = tid & 63;
    const int quad = lane >> 4;
    const int r16  = lane & 15;
    const int wr   = wave >> 1;
    const int wc   = wave & 1;

    const int m0 = blockIdx.y * 128;
    const int n0 = blockIdx.x * 128;

    const int srow = tid >> 2;
    const int scol = (tid & 3) * 8;

    const bf16_t* gA0 = A + (long)(m0 + srow) * S + scol;
    const bf16_t* gA1 = gA0 + (long)64 * S;
    const bf16_t* gB0 = Bm + (long)(n0 + srow) * S + scol;
    const bf16_t* gB1 = gB0 + (long)64 * S;
    bf16_t* lA = As + tid * 8;
    bf16_t* lB = Bs + tid * 8;

    f32x4 acc[4][4] = {};

    const int kbeg = ks * KC;
    const int kend = kbeg + KC;
    for (int k0 = kbeg; k0 < kend; k0 += 32) {
        load16_lds(gA0 + k0, lA);
        load16_lds(gA1 + k0, lA + 2048);
        load16_lds(gB0 + k0, lB);
        load16_lds(gB1 + k0, lB + 2048);
        __syncthreads();

        bf16x8 af[4], bfr[4];
#pragma unroll
        for (int i = 0; i < 4; i++)
            af[i] = *(const bf16x8*)(As + (wr * 64 + i * 16 + r16) * 32 + quad * 8);
#pragma unroll
        for (int j = 0; j < 4; j++)
            bfr[j] = *(const bf16x8*)(Bs + (wc * 64 + j * 16 + r16) * 32 + quad * 8);

#pragma unroll
        for (int i = 0; i < 4; i++)
#pragma unroll
            for (int j = 0; j < 4; j++)
                acc[i][j] = __builtin_amdgcn_mfma_f32_16x16x32_bf16(af[i], bfr[j], acc[i][j], 0, 0, 0);
        __syncthreads();
    }

    const long obase = (PMODE == 2) ? (long)b * D * S
                                    : ((long)ks * B_ + b) * (long)D * S;
#pragma unroll
    for (int i = 0; i < 4; i++) {
#pragma unroll
        for (int j = 0; j < 4; j++) {
            const int gn = n0 + wc * 64 + j * 16 + r16;
            float inv = 1.f;
            if (PMODE == 2) inv = 1.f / rowsum[b * S + gn];
#pragma unroll
            for (int reg = 0; reg < 4; reg++) {
                const int gm = m0 + wr * 64 + i * 16 + quad * 4 + reg;
                const long cidx = obase + (long)gm * S + gn;
                const float v = acc[i][j][reg];
                if (PMODE == 0) ((float*)outp)[cidx]  = v;
                if (PMODE == 1) ((bf16_t*)outp)[cidx] = (bf16_t)v;
                if (PMODE == 2) ((bf16_t*)outp)[cidx] = (bf16_t)(v * inv);
            }
        }
    }
}

// ---------------------------------------------------------------------------
// Reduce KS partials, normalize by rowsum[q], write bf16 T.
// idx layout: b*D*S + d*S + q.  PT = float or bf16.
// ---------------------------------------------------------------------------
template <typename PT, int KS>
__global__ __launch_bounds__(256) void reduce_norm(
    const PT* __restrict__ part, const float* __restrict__ rowsum,
    bf16_t* __restrict__ T)
{
    constexpr long TOT = (long)B_ * D_ * S_;
    constexpr long STR = TOT;
    const long i = ((long)blockIdx.x * 256 + threadIdx.x) * 4;
    if (i >= TOT) return;

    float s[4] = {0.f, 0.f, 0.f, 0.f};
#pragma unroll
    for (int ks = 0; ks < KS; ks++) {
        const PT* p = part + ks * STR + i;
#pragma unroll
        for (int t = 0; t < 4; t++) s[t] += (float)p[t];
    }
    const int b = (int)(i / ((long)D_ * S_));
    const int q = (int)(i & (S_ - 1));
    const float4 rs = *(const float4*)(rowsum + b * S_ + q);
    bf16_t o[4];
    o[0] = (bf16_t)(s[0] / rs.x);
    o[1] = (bf16_t)(s[1] / rs.y);
    o[2] = (bf16_t)(s[2] / rs.z);
    o[3] = (bf16_t)(s[3] / rs.w);
    *(uint2*)(T + i) = *(uint2*)o;
}

// ---------------------------------------------------------------------------
// Out projection: C = A @ B^T + bias, fp32 output. (kept from round 5)
// ---------------------------------------------------------------------------
__global__ __launch_bounds__(256) void out_gemm(
    const bf16_t* __restrict__ A, const bf16_t* __restrict__ B,
    const float* __restrict__ bias, float* __restrict__ C)
{
    constexpr int N = 512, K = 512;

    __shared__ bf16_t As[128 * 32];
    __shared__ bf16_t Bs[128 * 32];

    const int tid  = threadIdx.x;
    const int wave = tid >> 6;
    const int lane = tid & 63;
    const int quad = lane >> 4;
    const int r16  = lane & 15;
    const int wr   = wave >> 1;
    const int wc   = wave & 1;

    const int m0 = blockIdx.y * 128;
    const int n0 = blockIdx.x * 128;

    const int srow = tid >> 2;
    const int scol = (tid & 3) * 8;

    const bf16_t* gA0 = A + (long)(m0 + srow) * K + scol;
    const bf16_t* gA1 = gA0 + (long)64 * K;
    const bf16_t* gB0 = B + (long)(n0 + srow) * K + scol;
    const bf16_t* gB1 = gB0 + (long)64 * K;
    bf16_t* lA = As + tid * 8;
    bf16_t* lB = Bs + tid * 8;

    f32x4 acc[4][4] = {};

    for (int k0 = 0; k0 < K; k0 += 32) {
        load16_lds(gA0 + k0, lA);
        load16_lds(gA1 + k0, lA + 2048);
        load16_lds(gB0 + k0, lB);
        load16_lds(gB1 + k0, lB + 2048);
        __syncthreads();

        bf16x8 af[4], bfr[4];
#pragma unroll
        for (int i = 0; i < 4; i++)
            af[i] = *(const bf16x8*)(As + (wr * 64 + i * 16 + r16) * 32 + quad * 8);
#pragma unroll
        for (int j = 0; j < 4; j++)
            bfr[j] = *(const bf16x8*)(Bs + (wc * 64 + j * 16 + r16) * 32 + quad * 8);

#pragma unroll
        for (int i = 0; i < 4; i++)
#pragma unroll
            for (int j = 0; j < 4; j++)
                acc[i][j] = __builtin_amdgcn_mfma_f32_16x16x32_bf16(af[i], bfr[j], acc[i][j], 0, 0, 0);
        __syncthreads();
    }

#pragma unroll
    for (int i = 0; i < 4; i++) {
#pragma unroll
        for (int j = 0; j < 4; j++) {
            const int gn = n0 + wc * 64 + j * 16 + r16;
            const float bval = bias[gn];
#pragma unroll
            for (int reg = 0; reg < 4; reg++) {
                const int gm = m0 + wr * 64 + i * 16 + quad * 4 + reg;
                C[(long)gm * N + gn] = acc[i][j][reg] + bval;
            }
        }
    }
}

// ---------------------------------------------------------------------------
// V [B][rows][cols] -> VT [B][cols][rows]
// ---------------------------------------------------------------------------
__global__ __launch_bounds__(256) void transpose_k(
    const bf16_t* __restrict__ in, bf16_t* __restrict__ out, int rows, int cols)
{
    __shared__ bf16_t tile[32][33];
    const int b = blockIdx.z;
    in  += (long)b * rows * cols;
    out += (long)b * rows * cols;
    const int r0 = blockIdx.y * 32;
    const int c0 = blockIdx.x * 32;
    const int tx = threadIdx.x;
    const int ty = threadIdx.y;
#pragma unroll
    for (int i = 0; i < 4; i++)
        tile[ty + 8 * i][tx] = in[(long)(r0 + ty + 8 * i) * cols + c0 + tx];
    __syncthreads();
#pragma unroll
    for (int i = 0; i < 4; i++)
        out[(long)(c0 + ty + 8 * i) * rows + r0 + tx] = tile[tx][ty + 8 * i];
}

// ---------------------------------------------------------------------------
extern "C" void kernel_launch(void* const* d_in, const int* in_sizes, int n_in,
                              void* d_out, int out_size, void* d_ws, size_t ws_size,
                              hipStream_t stream)
{
    constexpr int B = B_, S = S_, D = D_;
    constexpr int BS = BS_;
    constexpr long QKV_ELEMS = (long)BS * D;   // 4 Mi
    constexpr long W_ELEMS   = (long)D * D;    // 256 Ki
    constexpr long SC_ELEMS  = (long)BS * S;   // 32 Mi

    const float* x_raw = (const float*)d_in[0];
    const float* mask  = (const float*)d_in[1];
    const float* Wq    = (const float*)d_in[2];
    const float* bq    = (const float*)d_in[3];
    const float* Wk    = (const float*)d_in[4];
    const float* bk    = (const float*)d_in[5];
    const float* Wv    = (const float*)d_in[6];
    const float* bv    = (const float*)d_in[7];
    const float* Wo    = (const float*)d_in[8];
    const float* bo    = (const float*)d_in[9];

    char* ws = (char*)d_ws;
    bf16_t* SC  = (bf16_t*)ws;                       ws += SC_ELEMS * 2;     // 64 MiB
    bf16_t* VT  = (bf16_t*)ws;                       ws += QKV_ELEMS * 2;    // 8
    bf16_t* Q   = (bf16_t*)ws;                       ws += QKV_ELEMS * 2;    // 8
    bf16_t* Kp  = (bf16_t*)ws;                       ws += QKV_ELEMS * 2;    // 8
    bf16_t* V   = (bf16_t*)ws;                       ws += QKV_ELEMS * 2;    // 8 (aliased as T)
    bf16_t* T   = V;                                 // V dead after transpose
    bf16_t* Xc  = (bf16_t*)ws;                       ws += QKV_ELEMS * 2;    // 8
    bf16_t* Wqc = (bf16_t*)ws;                       ws += W_ELEMS * 2;
    bf16_t* Wkc = (bf16_t*)ws;                       ws += W_ELEMS * 2;
    bf16_t* Wvc = (bf16_t*)ws;                       ws += W_ELEMS * 2;
    bf16_t* Woc = (bf16_t*)ws;                       ws += W_ELEMS * 2;
    float*  rowsum = (float*)ws;                     ws += (long)BS * 4;     // 32 KB
    void*   part = (void*)ws;
    const size_t used_base = (size_t)(ws - (char*)d_ws);
    constexpr long PART_ELEMS = 4L * B_ * D_ * S_;   // KS=4
    const int tier = (ws_size >= used_base + PART_ELEMS * 4) ? 0
                   : (ws_size >= used_base + PART_ELEMS * 2) ? 1 : 2;

    const float scale = 0.044194173824159216f; // 1/sqrt(512)
    dim3 blk(256);

    // 1) fp32 -> bf16 copies
    cvt_to_bf16<<<dim3((int)(QKV_ELEMS / 1024)), blk, 0, stream>>>(x_raw, Xc, QKV_ELEMS);
    cvt_to_bf16<<<dim3((int)(W_ELEMS / 1024)), blk, 0, stream>>>(Wq, Wqc, W_ELEMS);
    cvt_to_bf16<<<dim3((int)(W_ELEMS / 1024)), blk, 0, stream>>>(Wk, Wkc, W_ELEMS);
    cvt_to_bf16<<<dim3((int)(W_ELEMS / 1024)), blk, 0, stream>>>(Wv, Wvc, W_ELEMS);
    cvt_to_bf16<<<dim3((int)(W_ELEMS / 1024)), blk, 0, stream>>>(Wo, Woc, W_ELEMS);

    // 2) fused QKV projections
    qkv_gemm<<<dim3(12, 64), blk, 0, stream>>>(Xc, Wqc, Wkc, Wvc, bq, bk, bv, Q, Kp, V);

    // 3) V^T per batch
    transpose_k<<<dim3(D / 32, S / 32, B), dim3(32, 8), 0, stream>>>(V, VT, S, D);

    // 4) zero rowsum, then scores GEMM with fused mask+exp+rowsum
    hipMemsetAsync(rowsum, 0, (long)BS * 4, stream);
    scores_gemm<<<dim3(S / 128, S / 128, B), blk, 0, stream>>>(Q, Kp, mask, SC, rowsum, scale);

    // 5) PV (split-K if workspace allows) + normalize
    if (tier == 0) {
        pv_gemm<0, 4><<<dim3(S / 128, D / 128, B * 4), blk, 0, stream>>>(VT, SC, rowsum, part);
        reduce_norm<float, 4><<<dim3((int)(QKV_ELEMS / 1024)), blk, 0, stream>>>(
            (const float*)part, rowsum, T);
    } else if (tier == 1) {
        pv_gemm<1, 4><<<dim3(S / 128, D / 128, B * 4), blk, 0, stream>>>(VT, SC, rowsum, part);
        reduce_norm<bf16_t, 4><<<dim3((int)(QKV_ELEMS / 1024)), blk, 0, stream>>>(
            (const bf16_t*)part, rowsum, T);
    } else {
        pv_gemm<2, 1><<<dim3(S / 128, D / 128, B), blk, 0, stream>>>(VT, SC, rowsum, T);
    }

    // 6) out = flat(T)[BS,D] @ Wo^T + bo  -> fp32 d_out
    out_gemm<<<dim3(4, 64), blk, 0, stream>>>(T, Woc, bo, (float*)d_out);
}

// Round 7
// 394.160 us; speedup vs baseline: 1.4004x; 1.0022x over previous
//
#include <hip/hip_runtime.h>
#include <hip/hip_bf16.h>
#include <math.h>

typedef __bf16 bf16_t;
typedef __attribute__((ext_vector_type(8))) __bf16 bf16x8;
typedef __attribute__((ext_vector_type(4))) float f32x4;

constexpr int B_ = 2, S_ = 4096, D_ = 512;
constexpr int BS_ = B_ * S_;

// Async global->LDS 16B copy. LDS dest must be wave-uniform base + lane*16.
__device__ __forceinline__ void load16_lds(const bf16_t* g, bf16_t* l) {
    __builtin_amdgcn_global_load_lds(
        (const __attribute__((address_space(1))) void*)g,
        (__attribute__((address_space(3))) void*)l, 16, 0, 0);
}

// ---------------------------------------------------------------------------
// One-shot fp32->bf16 conversion of x + Wq + Wk + Wv + Wo into a CONTIGUOUS
// bf16 region starting at dst (Xc | Wqc | Wkc | Wvc | Woc).
// ---------------------------------------------------------------------------
__global__ __launch_bounds__(256) void cvt_all(
    const float* __restrict__ x, const float* __restrict__ Wq,
    const float* __restrict__ Wk, const float* __restrict__ Wv,
    const float* __restrict__ Wo, bf16_t* __restrict__ dst)
{
    constexpr long QKV = (long)BS_ * D_;       // 4 Mi
    constexpr long WE  = (long)D_ * D_;        // 256 Ki = 2^18
    const long i = ((long)blockIdx.x * 256 + threadIdx.x) * 4;
    const float* src;
    long o;
    if (i < QKV) { src = x; o = i; }
    else {
        const long j = i - QKV;
        const int w = (int)(j >> 18);
        o = j & (WE - 1);
        src = (w == 0) ? Wq : (w == 1) ? Wk : (w == 2) ? Wv : Wo;
    }
    const float4 v = *(const float4*)(src + o);
    bf16_t out[4] = {(bf16_t)v.x, (bf16_t)v.y, (bf16_t)v.z, (bf16_t)v.w};
    *(uint2*)(dst + i) = *(uint2*)out;
}

// ---------------------------------------------------------------------------
// Pack mask>0.95 into a byte mask (pure streaming, full BW).
// ---------------------------------------------------------------------------
__global__ __launch_bounds__(256) void pack_mask(
    const float* __restrict__ mask, unsigned char* __restrict__ bm)
{
    const long i = ((long)blockIdx.x * 256 + threadIdx.x) * 16;
    unsigned char o[16];
#pragma unroll
    for (int c = 0; c < 4; c++) {
        const float4 v = *(const float4*)(mask + i + c * 4);
        o[c * 4 + 0] = v.x > 0.95f;
        o[c * 4 + 1] = v.y > 0.95f;
        o[c * 4 + 2] = v.z > 0.95f;
        o[c * 4 + 3] = v.w > 0.95f;
    }
    *(uint4*)(bm + i) = *(uint4*)o;
}

// ---------------------------------------------------------------------------
// Fused QKV projection: X[8192,512] @ {Wq,Wk,Wv}^T + {bq,bk,bv}.
// ---------------------------------------------------------------------------
__global__ __launch_bounds__(256) void qkv_gemm(
    const bf16_t* __restrict__ X,
    const bf16_t* __restrict__ Wq, const bf16_t* __restrict__ Wk, const bf16_t* __restrict__ Wv,
    const float* __restrict__ bq, const float* __restrict__ bk, const float* __restrict__ bv,
    bf16_t* __restrict__ Q, bf16_t* __restrict__ Kout, bf16_t* __restrict__ V)
{
    constexpr int K = 512, N = 512;
    const int sel = blockIdx.x >> 2;
    const bf16_t* B = (sel == 0) ? Wq : (sel == 1) ? Wk : Wv;
    const float* bias = (sel == 0) ? bq : (sel == 1) ? bk : bv;
    bf16_t* C = (sel == 0) ? Q : (sel == 1) ? Kout : V;

    __shared__ bf16_t As[128 * 32];
    __shared__ bf16_t Bs[128 * 32];

    const int tid  = threadIdx.x;
    const int wave = tid >> 6;
    const int lane = tid & 63;
    const int quad = lane >> 4;
    const int r16  = lane & 15;
    const int wr   = wave >> 1;
    const int wc   = wave & 1;

    const int m0 = blockIdx.y * 128;
    const int n0 = (blockIdx.x & 3) * 128;

    const int srow = tid >> 2;
    const int scol = (tid & 3) * 8;

    const bf16_t* gA0 = X + (long)(m0 + srow) * K + scol;
    const bf16_t* gA1 = gA0 + (long)64 * K;
    const bf16_t* gB0 = B + (long)(n0 + srow) * K + scol;
    const bf16_t* gB1 = gB0 + (long)64 * K;
    bf16_t* lA = As + tid * 8;
    bf16_t* lB = Bs + tid * 8;

    f32x4 acc[4][4] = {};

    for (int k0 = 0; k0 < K; k0 += 32) {
        load16_lds(gA0 + k0, lA);
        load16_lds(gA1 + k0, lA + 2048);
        load16_lds(gB0 + k0, lB);
        load16_lds(gB1 + k0, lB + 2048);
        __syncthreads();

        bf16x8 af[4], bfr[4];
#pragma unroll
        for (int i = 0; i < 4; i++)
            af[i] = *(const bf16x8*)(As + (wr * 64 + i * 16 + r16) * 32 + quad * 8);
#pragma unroll
        for (int j = 0; j < 4; j++)
            bfr[j] = *(const bf16x8*)(Bs + (wc * 64 + j * 16 + r16) * 32 + quad * 8);

#pragma unroll
        for (int i = 0; i < 4; i++)
#pragma unroll
            for (int j = 0; j < 4; j++)
                acc[i][j] = __builtin_amdgcn_mfma_f32_16x16x32_bf16(af[i], bfr[j], acc[i][j], 0, 0, 0);
        __syncthreads();
    }

#pragma unroll
    for (int i = 0; i < 4; i++) {
#pragma unroll
        for (int j = 0; j < 4; j++) {
            const int gn = n0 + wc * 64 + j * 16 + r16;
            const float bval = bias[gn];
#pragma unroll
            for (int reg = 0; reg < 4; reg++) {
                const int gm = m0 + wr * 64 + i * 16 + quad * 4 + reg;
                C[(long)gm * N + gn] = (bf16_t)(acc[i][j][reg] + bval);
            }
        }
    }
}

// ---------------------------------------------------------------------------
// Scores GEMM with fused mask + exp + row-sum accumulation.
// E[b,q,k] = keep ? exp(scale * (Q.K)) : 0   (bf16, unnormalized)
// rowsum[b*S + q] += per-row sums (fp32 atomics, zeroed beforehand).
// MT = unsigned char (byte mask) or float (raw fp32 mask, keep if >0.95).
// ---------------------------------------------------------------------------
template <typename MT>
__global__ __launch_bounds__(256) void scores_gemm(
    const bf16_t* __restrict__ Q, const bf16_t* __restrict__ Km,
    const MT* __restrict__ mask, bf16_t* __restrict__ SC,
    float* __restrict__ rowsum, float scale)
{
    constexpr int S = S_, K = D_;
    const int b = blockIdx.z;
    const bf16_t* A = Q + (long)b * S * K;
    const bf16_t* Bm = Km + (long)b * S * K;

    __shared__ char smem[16384];
    bf16_t* As = (bf16_t*)smem;
    bf16_t* Bs = (bf16_t*)(smem + 8192);

    const int tid  = threadIdx.x;
    const int wave = tid >> 6;
    const int lane = tid & 63;
    const int quad = lane >> 4;
    const int r16  = lane & 15;
    const int wr   = wave >> 1;
    const int wc   = wave & 1;

    const int m0 = blockIdx.y * 128;
    const int n0 = blockIdx.x * 128;

    const int srow = tid >> 2;
    const int scol = (tid & 3) * 8;

    const bf16_t* gA0 = A + (long)(m0 + srow) * K + scol;
    const bf16_t* gA1 = gA0 + (long)64 * K;
    const bf16_t* gB0 = Bm + (long)(n0 + srow) * K + scol;
    const bf16_t* gB1 = gB0 + (long)64 * K;
    bf16_t* lA = As + tid * 8;
    bf16_t* lB = Bs + tid * 8;

    f32x4 acc[4][4] = {};

    for (int k0 = 0; k0 < K; k0 += 32) {
        load16_lds(gA0 + k0, lA);
        load16_lds(gA1 + k0, lA + 2048);
        load16_lds(gB0 + k0, lB);
        load16_lds(gB1 + k0, lB + 2048);
        __syncthreads();

        bf16x8 af[4], bfr[4];
#pragma unroll
        for (int i = 0; i < 4; i++)
            af[i] = *(const bf16x8*)(As + (wr * 64 + i * 16 + r16) * 32 + quad * 8);
#pragma unroll
        for (int j = 0; j < 4; j++)
            bfr[j] = *(const bf16x8*)(Bs + (wc * 64 + j * 16 + r16) * 32 + quad * 8);

#pragma unroll
        for (int i = 0; i < 4; i++)
#pragma unroll
            for (int j = 0; j < 4; j++)
                acc[i][j] = __builtin_amdgcn_mfma_f32_16x16x32_bf16(af[i], bfr[j], acc[i][j], 0, 0, 0);
        __syncthreads();
    }

    // Epilogue via per-wave LDS slice: coalesced mask loads + bf16x8 stores.
    float* wlds = (float*)smem + wave * 1024;   // 16 rows x 64 cols fp32
    const int erow = lane >> 2;                 // 0..15
    const int ecg  = lane & 3;                  // col group (16 cols)
    const long mbase = (long)b * S * S;

#pragma unroll
    for (int i = 0; i < 4; i++) {
#pragma unroll
        for (int j = 0; j < 4; j++)
#pragma unroll
            for (int reg = 0; reg < 4; reg++)
                wlds[(quad * 4 + reg) * 64 + j * 16 + r16] = acc[i][j][reg];
        __syncthreads();

        float v[16];
#pragma unroll
        for (int c = 0; c < 4; c++) {
            const float4 t = *(const float4*)(wlds + erow * 64 + ecg * 16 + c * 4);
            v[c * 4 + 0] = t.x; v[c * 4 + 1] = t.y;
            v[c * 4 + 2] = t.z; v[c * 4 + 3] = t.w;
        }

        const int gm = m0 + wr * 64 + i * 16 + erow;
        const int gn = n0 + wc * 64 + ecg * 16;

        float e[16];
        if (sizeof(MT) == 1) {
            const uint4 mb = *(const uint4*)((const unsigned char*)mask + mbase + (long)gm * S + gn);
            const unsigned char* mk = (const unsigned char*)&mb;
#pragma unroll
            for (int t = 0; t < 16; t++)
                e[t] = mk[t] ? __expf(v[t] * scale) : 0.f;
        } else {
            const float* mp = (const float*)mask + mbase + (long)gm * S + gn;
#pragma unroll
            for (int c = 0; c < 4; c++) {
                const float4 mk = *(const float4*)(mp + c * 4);
                e[c * 4 + 0] = (mk.x > 0.95f) ? __expf(v[c * 4 + 0] * scale) : 0.f;
                e[c * 4 + 1] = (mk.y > 0.95f) ? __expf(v[c * 4 + 1] * scale) : 0.f;
                e[c * 4 + 2] = (mk.z > 0.95f) ? __expf(v[c * 4 + 2] * scale) : 0.f;
                e[c * 4 + 3] = (mk.w > 0.95f) ? __expf(v[c * 4 + 3] * scale) : 0.f;
            }
        }

        bf16x8 o0, o1;
        float rsum = 0.f;
#pragma unroll
        for (int t = 0; t < 8; t++) {
            rsum += e[t] + e[t + 8];
            o0[t] = (bf16_t)e[t];
            o1[t] = (bf16_t)e[t + 8];
        }
        bf16_t* cp = SC + mbase + (long)gm * S + gn;
        *(bf16x8*)cp       = o0;
        *(bf16x8*)(cp + 8) = o1;

        rsum += __shfl_xor(rsum, 1, 64);
        rsum += __shfl_xor(rsum, 2, 64);
        if (ecg == 0) atomicAdd(&rowsum[b * S + gm], rsum);
        __syncthreads();
    }
}

// ---------------------------------------------------------------------------
// PV split-K. A = VT [D,S] per batch; B = E [S(q) x S(k)]; out [D,S].
// PMODE 0: fp32 raw partial; PMODE 2: direct bf16 normalized (KS==1);
// PMODE 3: bf16 NORMALIZED partial (rowsum complete before launch).
// ---------------------------------------------------------------------------
template <int PMODE, int KS>
__global__ __launch_bounds__(256) void pv_gemm(
    const bf16_t* __restrict__ VT, const bf16_t* __restrict__ SC,
    const float* __restrict__ rowsum, void* __restrict__ outp)
{
    constexpr int S = S_, D = D_;
    constexpr int KC = S / KS;
    const int z  = blockIdx.z;
    const int b  = z / KS;
    const int ks = z % KS;

    const bf16_t* A  = VT + (long)b * D * S;
    const bf16_t* Bm = SC + (long)b * S * S;

    __shared__ bf16_t As[128 * 32];
    __shared__ bf16_t Bs[128 * 32];

    const int tid  = threadIdx.x;
    const int wave = tid >> 6;
    const int lane = tid & 63;
    const int quad = lane >> 4;
    const int r16  = lane & 15;
    const int wr   = wave >> 1;
    const int wc   = wave & 1;

    const int m0 = blockIdx.y * 128;
    const int n0 = blockIdx.x * 128;

    const int srow = tid >> 2;
    const int scol = (tid & 3) * 8;

    const bf16_t* gA0 = A + (long)(m0 + srow) * S + scol;
    const bf16_t* gA1 = gA0 + (long)64 * S;
    const bf16_t* gB0 = Bm + (long)(n0 + srow) * S + scol;
    const bf16_t* gB1 = gB0 + (long)64 * S;
    bf16_t* lA = As + tid * 8;
    bf16_t* lB = Bs + tid * 8;

    f32x4 acc[4][4] = {};

    const int kbeg = ks * KC;
    const int kend = kbeg + KC;
    for (int k0 = kbeg; k0 < kend; k0 += 32) {
        load16_lds(gA0 + k0, lA);
        load16_lds(gA1 + k0, lA + 2048);
        load16_lds(gB0 + k0, lB);
        load16_lds(gB1 + k0, lB + 2048);
        __syncthreads();

        bf16x8 af[4], bfr[4];
#pragma unroll
        for (int i = 0; i < 4; i++)
            af[i] = *(const bf16x8*)(As + (wr * 64 + i * 16 + r16) * 32 + quad * 8);
#pragma unroll
        for (int j = 0; j < 4; j++)
            bfr[j] = *(const bf16x8*)(Bs + (wc * 64 + j * 16 + r16) * 32 + quad * 8);

#pragma unroll
        for (int i = 0; i < 4; i++)
#pragma unroll
            for (int j = 0; j < 4; j++)
                acc[i][j] = __builtin_amdgcn_mfma_f32_16x16x32_bf16(af[i], bfr[j], acc[i][j], 0, 0, 0);
        __syncthreads();
    }

    const long obase = (PMODE == 2) ? (long)b * D * S
                                    : ((long)ks * B_ + b) * (long)D * S;
#pragma unroll
    for (int i = 0; i < 4; i++) {
#pragma unroll
        for (int j = 0; j < 4; j++) {
            const int gn = n0 + wc * 64 + j * 16 + r16;
            float inv = 1.f;
            if (PMODE == 2 || PMODE == 3) inv = 1.f / rowsum[b * S + gn];
#pragma unroll
            for (int reg = 0; reg < 4; reg++) {
                const int gm = m0 + wr * 64 + i * 16 + quad * 4 + reg;
                const long cidx = obase + (long)gm * S + gn;
                const float v = acc[i][j][reg];
                if (PMODE == 0) ((float*)outp)[cidx]  = v;
                if (PMODE == 2) ((bf16_t*)outp)[cidx] = (bf16_t)(v * inv);
                if (PMODE == 3) ((bf16_t*)outp)[cidx] = (bf16_t)(v * inv);
            }
        }
    }
}

// ---------------------------------------------------------------------------
// Reduce KS partials -> bf16 T.  NORM=1: divide by rowsum (raw fp32 partials);
// NORM=0: partials already normalized (bf16), just sum.
// ---------------------------------------------------------------------------
template <typename PT, int KS, int NORM>
__global__ __launch_bounds__(256) void reduce_k(
    const PT* __restrict__ part, const float* __restrict__ rowsum,
    bf16_t* __restrict__ T)
{
    constexpr long TOT = (long)B_ * D_ * S_;
    const long i = ((long)blockIdx.x * 256 + threadIdx.x) * 4;
    if (i >= TOT) return;

    float s[4] = {0.f, 0.f, 0.f, 0.f};
#pragma unroll
    for (int ks = 0; ks < KS; ks++) {
        const PT* p = part + ks * TOT + i;
#pragma unroll
        for (int t = 0; t < 4; t++) s[t] += (float)p[t];
    }
    bf16_t o[4];
    if (NORM) {
        const int b = (int)(i / ((long)D_ * S_));
        const int q = (int)(i & (S_ - 1));
        const float4 rs = *(const float4*)(rowsum + b * S_ + q);
        o[0] = (bf16_t)(s[0] / rs.x);
        o[1] = (bf16_t)(s[1] / rs.y);
        o[2] = (bf16_t)(s[2] / rs.z);
        o[3] = (bf16_t)(s[3] / rs.w);
    } else {
        o[0] = (bf16_t)s[0]; o[1] = (bf16_t)s[1];
        o[2] = (bf16_t)s[2]; o[3] = (bf16_t)s[3];
    }
    *(uint2*)(T + i) = *(uint2*)o;
}

// ---------------------------------------------------------------------------
// Out projection: C = A @ B^T + bias, fp32 output.
// ---------------------------------------------------------------------------
__global__ __launch_bounds__(256) void out_gemm(
    const bf16_t* __restrict__ A, const bf16_t* __restrict__ B,
    const float* __restrict__ bias, float* __restrict__ C)
{
    constexpr int N = 512, K = 512;

    __shared__ bf16_t As[128 * 32];
    __shared__ bf16_t Bs[128 * 32];

    const int tid  = threadIdx.x;
    const int wave = tid >> 6;
    const int lane = tid & 63;
    const int quad = lane >> 4;
    const int r16  = lane & 15;
    const int wr   = wave >> 1;
    const int wc   = wave & 1;

    const int m0 = blockIdx.y * 128;
    const int n0 = blockIdx.x * 128;

    const int srow = tid >> 2;
    const int scol = (tid & 3) * 8;

    const bf16_t* gA0 = A + (long)(m0 + srow) * K + scol;
    const bf16_t* gA1 = gA0 + (long)64 * K;
    const bf16_t* gB0 = B + (long)(n0 + srow) * K + scol;
    const bf16_t* gB1 = gB0 + (long)64 * K;
    bf16_t* lA = As + tid * 8;
    bf16_t* lB = Bs + tid * 8;

    f32x4 acc[4][4] = {};

    for (int k0 = 0; k0 < K; k0 += 32) {
        load16_lds(gA0 + k0, lA);
        load16_lds(gA1 + k0, lA + 2048);
        load16_lds(gB0 + k0, lB);
        load16_lds(gB1 + k0, lB + 2048);
        __syncthreads();

        bf16x8 af[4], bfr[4];
#pragma unroll
        for (int i = 0; i < 4; i++)
            af[i] = *(const bf16x8*)(As + (wr * 64 + i * 16 + r16) * 32 + quad * 8);
#pragma unroll
        for (int j = 0; j < 4; j++)
            bfr[j] = *(const bf16x8*)(Bs + (wc * 64 + j * 16 + r16) * 32 + quad * 8);

#pragma unroll
        for (int i = 0; i < 4; i++)
#pragma unroll
            for (int j = 0; j < 4; j++)
                acc[i][j] = __builtin_amdgcn_mfma_f32_16x16x32_bf16(af[i], bfr[j], acc[i][j], 0, 0, 0);
        __syncthreads();
    }

#pragma unroll
    for (int i = 0; i < 4; i++) {
#pragma unroll
        for (int j = 0; j < 4; j++) {
            const int gn = n0 + wc * 64 + j * 16 + r16;
            const float bval = bias[gn];
#pragma unroll
            for (int reg = 0; reg < 4; reg++) {
                const int gm = m0 + wr * 64 + i * 16 + quad * 4 + reg;
                C[(long)gm * N + gn] = acc[i][j][reg] + bval;
            }
        }
    }
}

// ---------------------------------------------------------------------------
// V [B][rows][cols] -> VT [B][cols][rows]
// ---------------------------------------------------------------------------
__global__ __launch_bounds__(256) void transpose_k(
    const bf16_t* __restrict__ in, bf16_t* __restrict__ out, int rows, int cols)
{
    __shared__ bf16_t tile[32][33];
    const int b = blockIdx.z;
    in  += (long)b * rows * cols;
    out += (long)b * rows * cols;
    const int r0 = blockIdx.y * 32;
    const int c0 = blockIdx.x * 32;
    const int tx = threadIdx.x;
    const int ty = threadIdx.y;
#pragma unroll
    for (int i = 0; i < 4; i++)
        tile[ty + 8 * i][tx] = in[(long)(r0 + ty + 8 * i) * cols + c0 + tx];
    __syncthreads();
#pragma unroll
    for (int i = 0; i < 4; i++)
        out[(long)(c0 + ty + 8 * i) * rows + r0 + tx] = tile[tx][ty + 8 * i];
}

// ---------------------------------------------------------------------------
extern "C" void kernel_launch(void* const* d_in, const int* in_sizes, int n_in,
                              void* d_out, int out_size, void* d_ws, size_t ws_size,
                              hipStream_t stream)
{
    constexpr int B = B_, S = S_, D = D_;
    constexpr int BS = BS_;
    constexpr long QKV_ELEMS = (long)BS * D;   // 4 Mi
    constexpr long W_ELEMS   = (long)D * D;    // 256 Ki
    constexpr long SC_ELEMS  = (long)BS * S;   // 32 Mi
    constexpr long MASK_N    = (long)BS * S;   // 32 Mi elems

    const float* x_raw = (const float*)d_in[0];
    const float* mask  = (const float*)d_in[1];
    const float* Wq    = (const float*)d_in[2];
    const float* bq    = (const float*)d_in[3];
    const float* Wk    = (const float*)d_in[4];
    const float* bk    = (const float*)d_in[5];
    const float* Wv    = (const float*)d_in[6];
    const float* bv    = (const float*)d_in[7];
    const float* Wo    = (const float*)d_in[8];
    const float* bo    = (const float*)d_in[9];

    char* ws = (char*)d_ws;
    bf16_t* SC  = (bf16_t*)ws;                       ws += SC_ELEMS * 2;     // 64 MiB
    bf16_t* VT  = (bf16_t*)ws;                       ws += QKV_ELEMS * 2;    // 8
    bf16_t* Q   = (bf16_t*)ws;                       ws += QKV_ELEMS * 2;    // 8
    bf16_t* Kp  = (bf16_t*)ws;                       ws += QKV_ELEMS * 2;    // 8
    bf16_t* V   = (bf16_t*)ws;                       ws += QKV_ELEMS * 2;    // 8 (aliased as T)
    bf16_t* T   = V;
    bf16_t* Xc  = (bf16_t*)ws;                       ws += QKV_ELEMS * 2;    // 8 (contiguous w/ W's)
    bf16_t* Wqc = (bf16_t*)ws;                       ws += W_ELEMS * 2;
    bf16_t* Wkc = (bf16_t*)ws;                       ws += W_ELEMS * 2;
    bf16_t* Wvc = (bf16_t*)ws;                       ws += W_ELEMS * 2;
    bf16_t* Woc = (bf16_t*)ws;                       ws += W_ELEMS * 2;
    float*  rowsum = (float*)ws;                     ws += (long)BS * 4;     // 32 KB
    // bmask (33.5 MB, live only during scores) OVERLAYS the partial region
    // (live only during pv/reduce) — lifetimes are disjoint.
    unsigned char* bmask = (unsigned char*)ws;
    void* part = (void*)ws;
    const size_t used_base = (size_t)(ws - (char*)d_ws);

    constexpr long PART_ELEMS = 4L * B_ * D_ * S_;   // KS=4
    // path A: byte mask + normalized bf16 partials (needs max(33.5MB, 32MB))
    // path B: fp32 mask + raw fp32 partials (round-6 tier0)
    // path C: fp32 mask + direct KS=1
    const int path = (ws_size >= used_base + MASK_N) ? 0
                   : (ws_size >= used_base + PART_ELEMS * 4) ? 1 : 2;

    const float scale = 0.044194173824159216f; // 1/sqrt(512)
    dim3 blk(256);

    // 1) fp32 -> bf16 (x + 4 weight matrices, one launch)
    cvt_all<<<dim3((int)((QKV_ELEMS + 4 * W_ELEMS) / 1024)), blk, 0, stream>>>(
        x_raw, Wq, Wk, Wv, Wo, Xc);

    // 2) byte-mask pack (path A)
    if (path == 0)
        pack_mask<<<dim3((int)(MASK_N / 4096)), blk, 0, stream>>>(mask, bmask);

    // 3) fused QKV projections
    qkv_gemm<<<dim3(12, 64), blk, 0, stream>>>(Xc, Wqc, Wkc, Wvc, bq, bk, bv, Q, Kp, V);

    // 4) V^T per batch
    transpose_k<<<dim3(D / 32, S / 32, B), dim3(32, 8), 0, stream>>>(V, VT, S, D);

    // 5) zero rowsum, then scores GEMM with fused mask+exp+rowsum
    hipMemsetAsync(rowsum, 0, (long)BS * 4, stream);
    if (path == 0)
        scores_gemm<unsigned char><<<dim3(S / 128, S / 128, B), blk, 0, stream>>>(
            Q, Kp, bmask, SC, rowsum, scale);
    else
        scores_gemm<float><<<dim3(S / 128, S / 128, B), blk, 0, stream>>>(
            Q, Kp, mask, SC, rowsum, scale);

    // 6) PV + normalization
    if (path == 0) {
        pv_gemm<3, 4><<<dim3(S / 128, D / 128, B * 4), blk, 0, stream>>>(VT, SC, rowsum, part);
        reduce_k<bf16_t, 4, 0><<<dim3((int)(QKV_ELEMS / 1024)), blk, 0, stream>>>(
            (const bf16_t*)part, rowsum, T);
    } else if (path == 1) {
        pv_gemm<0, 4><<<dim3(S / 128, D / 128, B * 4), blk, 0, stream>>>(VT, SC, rowsum, part);
        reduce_k<float, 4, 1><<<dim3((int)(QKV_ELEMS / 1024)), blk, 0, stream>>>(
            (const float*)part, rowsum, T);
    } else {
        pv_gemm<2, 1><<<dim3(S / 128, D / 128, B), blk, 0, stream>>>(VT, SC, rowsum, T);
    }

    // 7) out = flat(T)[BS,D] @ Wo^T + bo  -> fp32 d_out
    out_gemm<<<dim3(4, 64), blk, 0, stream>>>(T, Woc, bo, (float*)d_out);
}